// Round 1
// baseline (693.461 us; speedup 1.0000x reference)
//
#include <hip/hip_runtime.h>

// Disable FMA contraction globally: the numpy f32 reference has no FMA, and
// the contact decision (dh <= 0) is discontinuous -> must match op-for-op.
#pragma clang fp contract(off)

static constexpr int Bc    = 512;
static constexpr int NPTSc = 2048;
static constexpr int Hc    = 256;
static constexpr int Wc    = 256;
static constexpr float DMAXF = 6.4f;
// Staged cells per plane. 6 planes * 2048 cells * 4B = 48 KiB LDS -> 3 wg/CU.
// Typical block bbox is ~36x36 = 1300 cells (sigma ~6 cells, range of 256
// normals ~5.7 sigma); P(bbox > 2048) < ~1% -> global fallback path.
static constexpr int CELLS = 2048;

__device__ __forceinline__ float bl(float g00, float g01, float g10, float g11,
                                    float wi, float wj) {
#pragma clang fp contract(off)
    // exact op ordering of the reference
    return g00 * (1.0f - wi) * (1.0f - wj)
         + g01 * (1.0f - wi) * wj
         + g10 * wi * (1.0f - wj)
         + g11 * wi * wj;
}

__global__ __launch_bounds__(256)
void phys_points(const float* __restrict__ x, const float* __restrict__ xd,
                 const float* __restrict__ R, const float* __restrict__ omega,
                 const float* __restrict__ rp,
                 const float* __restrict__ zg, const float* __restrict__ zgg,
                 const float* __restrict__ kg, const float* __restrict__ dg,
                 const float* __restrict__ mug,
                 const int* __restrict__ dparts, const float* __restrict__ ctrl,
                 float* __restrict__ outFs, float* __restrict__ outFf,
                 float* __restrict__ partial)
{
#pragma clang fp contract(off)
    __shared__ float sg[6 * CELLS];
    __shared__ int sbox[4];          // min_i, max_i, min_j, max_j

    const int tid = threadIdx.x;
    const int b = blockIdx.x >> 3;               // NPTS/256 = 8 blocks per batch
    const int n = ((blockIdx.x & 7) << 8) + tid;

    // per-batch scalars (broadcast loads, L1-served)
    float xb0 = x[b * 3 + 0], xb1 = x[b * 3 + 1], xb2 = x[b * 3 + 2];
    float xd0 = xd[b * 3 + 0], xd1 = xd[b * 3 + 1], xd2 = xd[b * 3 + 2];
    float om0 = omega[b * 3 + 0], om1 = omega[b * 3 + 1], om2 = omega[b * 3 + 2];
    float R00 = R[b * 9 + 0], R01 = R[b * 9 + 1], R02 = R[b * 9 + 2];
    float R10 = R[b * 9 + 3], R11 = R[b * 9 + 4], R12 = R[b * 9 + 5];
    float R20 = R[b * 9 + 6], R21 = R[b * 9 + 7], R22 = R[b * 9 + 8];

    const int part = dparts[n];
    const float cpart = ctrl[b * 4 + part];

    const int pbase = (b * NPTSc + n) * 3;
    float p0 = rp[pbase + 0], p1 = rp[pbase + 1], p2 = rp[pbase + 2];

    // x_points = R @ p + x  (left-to-right sum, then add x)
    float xp0 = (R00 * p0 + R01 * p1 + R02 * p2) + xb0;
    float xp1 = (R10 * p0 + R11 * p1 + R12 * p2) + xb1;
    float xp2 = (R20 * p0 + R21 * p1 + R22 * p2) + xb2;

    // r = x_points - x  (reference recomputes this incl. the +x/-x round-trip)
    float rx = xp0 - xb0, ry = xp1 - xb1, rz = xp2 - xb2;

    // bilinear indices
    float gi = (xp0 + DMAXF) / (2.0f * DMAXF) * 255.0f;
    gi = fminf(fmaxf(gi, 0.0f), 255.0f);
    float gj = (xp1 + DMAXF) / (2.0f * DMAXF) * 255.0f;
    gj = fminf(fmaxf(gj, 0.0f), 255.0f);
    int i0 = (int)floorf(gi); i0 = min(max(i0, 0), Hc - 2);
    int j0 = (int)floorf(gj); j0 = min(max(j0, 0), Wc - 2);
    float wi = gi - (float)i0;
    float wj = gj - (float)j0;

    // ---- block bbox of the gather footprint (i0..i0+1, j0..j0+1) ----
    int mni = i0, mxi = i0, mnj = j0, mxj = j0;
    #pragma unroll
    for (int off = 32; off > 0; off >>= 1) {
        mni = min(mni, __shfl_xor(mni, off, 64));
        mxi = max(mxi, __shfl_xor(mxi, off, 64));
        mnj = min(mnj, __shfl_xor(mnj, off, 64));
        mxj = max(mxj, __shfl_xor(mxj, off, 64));
    }
    if (tid == 0) { sbox[0] = 255; sbox[1] = 0; sbox[2] = 255; sbox[3] = 0; }
    __syncthreads();
    if ((tid & 63) == 0) {
        atomicMin(&sbox[0], mni); atomicMax(&sbox[1], mxi);
        atomicMin(&sbox[2], mnj); atomicMax(&sbox[3], mxj);
    }
    __syncthreads();
    const int bmin_i = sbox[0], bmin_j = sbox[2];
    const int ih = sbox[1] - bmin_i + 2;     // rows incl. the +1 corner row
    const int jw = sbox[3] - bmin_j + 2;     // cols incl. the +1 corner col
    const bool use_lds = (ih * jw) <= CELLS; // block-uniform branch

    const int gb  = b * (Hc * Wc);
    const int gb2 = b * (2 * Hc * Wc);
    const float* planes[6] = { zg + gb, kg + gb, dg + gb, mug + gb,
                               zgg + gb2, zgg + gb2 + Hc * Wc };

    float cv[6][4];   // 4 corner values for each of the 6 planes
    if (use_lds) {
        // coalesced staging of the bbox of all 6 planes into LDS
        const int tx = tid & 63, ty = tid >> 6;
        #pragma unroll
        for (int p = 0; p < 6; ++p) {
            const float* src = planes[p] + bmin_i * Wc + bmin_j;
            float* dst = sg + p * CELLS;
            for (int r = ty; r < ih; r += 4)
                for (int c = tx; c < jw; c += 64)
                    dst[r * jw + c] = src[r * Wc + c];
        }
        __syncthreads();
        const int la = (i0 - bmin_i) * jw + (j0 - bmin_j);
        #pragma unroll
        for (int p = 0; p < 6; ++p) {
            const float* s = sg + p * CELLS + la;
            cv[p][0] = s[0]; cv[p][1] = s[1];          // fuse -> ds_read2_b32
            cv[p][2] = s[jw]; cv[p][3] = s[jw + 1];
        }
    } else {
        // rare oversized-bbox fallback: exact previous global-gather path
        const int la = i0 * Wc + j0;
        #pragma unroll
        for (int p = 0; p < 6; ++p) {
            const float* s = planes[p] + la;
            cv[p][0] = s[0]; cv[p][1] = s[1];
            cv[p][2] = s[Wc]; cv[p][3] = s[Wc + 1];
        }
    }

    float zp  = bl(cv[0][0], cv[0][1], cv[0][2], cv[0][3], wi, wj);
    float kp  = bl(cv[1][0], cv[1][1], cv[1][2], cv[1][3], wi, wj);
    float dpv = bl(cv[2][0], cv[2][1], cv[2][2], cv[2][3], wi, wj);
    float mup = bl(cv[3][0], cv[3][1], cv[3][2], cv[3][3], wi, wj);
    float gx  = bl(cv[4][0], cv[4][1], cv[4][2], cv[4][3], wi, wj);
    float gy  = bl(cv[5][0], cv[5][1], cv[5][2], cv[5][3], wi, wj);

    float dh = xp2 - zp;
    bool on_grid = (xp0 >= -DMAXF) && (xp0 <= DMAXF) &&
                   (xp1 >= -DMAXF) && (xp1 <= DMAXF);
    float contact = ((dh <= 0.0f) && on_grid) ? 1.0f : 0.0f;

    // surface normal
    float nx = -gx, ny = -gy, nz = 1.0f;
    float nn = sqrtf(nx * nx + ny * ny + nz * nz);
    nx /= nn; ny /= nn; nz /= nn;

    // point velocity: xd + omega x r
    float vx = xd0 + (om1 * rz - om2 * ry);
    float vy = xd1 + (om2 * rx - om0 * rz);
    float vz = xd2 + (om0 * ry - om1 * rx);

    float xdn = vx * nx + vy * ny + vz * nz;
    float s = -(kp * dh + dpv * xdn);
    const float scale = contact * (1.0f / 2048.0f);  // contact in {0,1}; /2048 exact
    float Fs0 = (s * nx) * scale;
    float Fs1 = (s * ny) * scale;
    float Fs2 = (s * nz) * scale;

    float Nmag = sqrtf(Fs0 * Fs0 + Fs1 * Fs1 + Fs2 * Fs2);

    // thrust dir = normalize(R[:,0])
    float t0 = R00, t1 = R10, t2 = R20;
    float tn = sqrtf(t0 * t0 + t1 * t1 + t2 * t2);
    t0 /= tn; t1 /= tn; t2 /= tn;

    float dv0 = cpart * t0 - vx;
    float dv1 = cpart * t1 - vy;
    float dv2 = cpart * t2 - vz;
    float dvn = dv0 * nx + dv1 * ny + dv2 * nz;
    float dt0 = dv0 - dvn * nx;
    float dt1 = dv1 - dvn * ny;
    float dt2 = dv2 - dvn * nz;
    float mN = mup * Nmag;
    float Ff0 = mN * tanhf(dt0);
    float Ff1 = mN * tanhf(dt1);
    float Ff2 = mN * tanhf(dt2);

    // write per-point outputs (f32)
    outFs[pbase + 0] = Fs0;
    outFs[pbase + 1] = Fs1;
    outFs[pbase + 2] = Fs2;
    outFf[pbase + 0] = Ff0;
    outFf[pbase + 1] = Ff1;
    outFf[pbase + 2] = Ff2;

    // torque = cross(r, Fs + Ff)
    float Ft0 = Fs0 + Ff0, Ft1 = Fs1 + Ff1, Ft2 = Fs2 + Ff2;
    float vals[9];
    vals[0] = ry * Ft2 - rz * Ft1;
    vals[1] = rz * Ft0 - rx * Ft2;
    vals[2] = rx * Ft1 - ry * Ft0;
    vals[3] = Fs0; vals[4] = Fs1; vals[5] = Fs2;
    vals[6] = Ff0; vals[7] = Ff1; vals[8] = Ff2;

    // wave-64 butterfly reduction, then wave-leader writes its partial slot
    // (no atomics, no workspace memset needed: every slot written every launch)
    #pragma unroll
    for (int k = 0; k < 9; ++k) {
        float v = vals[k];
        #pragma unroll
        for (int off = 32; off > 0; off >>= 1)
            v += __shfl_xor(v, off, 64);
        vals[k] = v;
    }
    if ((tid & 63) == 0) {
        const int widx = ((blockIdx.x & 7) << 2) + (tid >> 6);   // 0..31 within batch
        float* pb = partial + ((size_t)(b * 32 + widx)) * 9;
        #pragma unroll
        for (int k = 0; k < 9; ++k) pb[k] = vals[k];
    }
}

__global__ __launch_bounds__(64)
void phys_final(const float* __restrict__ xd, const float* __restrict__ Imat,
                const float* __restrict__ partial,
                float* __restrict__ out_xd, float* __restrict__ out_xdd,
                float* __restrict__ out_omd)
{
#pragma clang fp contract(off)
    const int b = blockIdx.x;
    const int lane = threadIdx.x;

    float v[9];
    if (lane < 32) {
        const float* pb = partial + ((size_t)(b * 32 + lane)) * 9;
        #pragma unroll
        for (int k = 0; k < 9; ++k) v[k] = pb[k];
    } else {
        #pragma unroll
        for (int k = 0; k < 9; ++k) v[k] = 0.0f;
    }
    #pragma unroll
    for (int k = 0; k < 9; ++k) {
        float t = v[k];
        #pragma unroll
        for (int off = 32; off > 0; off >>= 1)
            t += __shfl_xor(t, off, 64);
        v[k] = t;
    }

    if (lane == 0) {
        float tq0 = v[0], tq1 = v[1], tq2 = v[2];
        float sFs0 = v[3], sFs1 = v[4], sFs2 = v[5];
        float sFf0 = v[6], sFf1 = v[7], sFf2 = v[8];

        float a00 = Imat[b * 9 + 0], a01 = Imat[b * 9 + 1], a02 = Imat[b * 9 + 2];
        float a10 = Imat[b * 9 + 3], a11 = Imat[b * 9 + 4], a12 = Imat[b * 9 + 5];
        float a20 = Imat[b * 9 + 6], a21 = Imat[b * 9 + 7], a22 = Imat[b * 9 + 8];

        // adjugate / determinant inverse (I is well-conditioned: A A^T + 2I)
        float c00 = a11 * a22 - a12 * a21;
        float c01 = a02 * a21 - a01 * a22;
        float c02 = a01 * a12 - a02 * a11;
        float c10 = a12 * a20 - a10 * a22;
        float c11 = a00 * a22 - a02 * a20;
        float c12 = a02 * a10 - a00 * a12;
        float c20 = a10 * a21 - a11 * a20;
        float c21 = a01 * a20 - a00 * a21;
        float c22 = a00 * a11 - a01 * a10;
        float det = a00 * c00 + a01 * c10 + a02 * c20;
        float id = 1.0f / det;

        float od0 = (c00 * tq0 + c01 * tq1 + c02 * tq2) * id;
        float od1 = (c10 * tq0 + c11 * tq1 + c12 * tq2) * id;
        float od2 = (c20 * tq0 + c21 * tq1 + c22 * tq2) * id;

        // F_cog = (grav + sum Fs) + sum Ff ; xdd = F_cog / MASS
        float fc0 = (0.0f + sFs0) + sFf0;
        float fc1 = (0.0f + sFs1) + sFf1;
        float fc2 = (-40.0f * 9.8f + sFs2) + sFf2;
        float xdd0 = fc0 / 40.0f, xdd1 = fc1 / 40.0f, xdd2 = fc2 / 40.0f;

        out_xd[b * 3 + 0] = xd[b * 3 + 0];
        out_xd[b * 3 + 1] = xd[b * 3 + 1];
        out_xd[b * 3 + 2] = xd[b * 3 + 2];
        out_xdd[b * 3 + 0] = xdd0;
        out_xdd[b * 3 + 1] = xdd1;
        out_xdd[b * 3 + 2] = xdd2;
        out_omd[b * 3 + 0] = od0;
        out_omd[b * 3 + 1] = od1;
        out_omd[b * 3 + 2] = od2;
    }
}

extern "C" void kernel_launch(void* const* d_in, const int* in_sizes, int n_in,
                              void* d_out, int out_size, void* d_ws, size_t ws_size,
                              hipStream_t stream)
{
    const float* x    = (const float*)d_in[0];
    const float* xd   = (const float*)d_in[1];
    const float* R    = (const float*)d_in[2];
    const float* om   = (const float*)d_in[3];
    const float* Imat = (const float*)d_in[4];
    const float* rp   = (const float*)d_in[5];
    const float* zg   = (const float*)d_in[6];
    const float* zgg  = (const float*)d_in[7];
    const float* kg   = (const float*)d_in[8];
    const float* dg   = (const float*)d_in[9];
    const float* mug  = (const float*)d_in[10];
    const int* dparts = (const int*)d_in[11];
    const float* ctrl = (const float*)d_in[12];

    float* out = (float*)d_out;
    const int B3 = Bc * 3;
    float* out_xd  = out;
    float* out_xdd = out + B3;
    float* out_omd = out + 2 * B3;
    float* outFs   = out + 3 * B3;
    float* outFf   = out + 3 * B3 + (size_t)Bc * NPTSc * 3;

    // per-wave partials: Bc * 32 waves * 9 floats = 576 KiB of workspace.
    // Every slot is written unconditionally each launch -> no memset needed.
    float* partial = (float*)d_ws;

    phys_points<<<Bc * NPTSc / 256, 256, 0, stream>>>(
        x, xd, R, om, rp, zg, zgg, kg, dg, mug, dparts, ctrl, outFs, outFf, partial);
    phys_final<<<Bc, 64, 0, stream>>>(
        xd, Imat, partial, out_xd, out_xdd, out_omd);
}

// Round 2
// 586.590 us; speedup vs baseline: 1.1822x; 1.1822x over previous
//
#include <hip/hip_runtime.h>

// Disable FMA contraction globally: the numpy f32 reference has no FMA, and
// the contact decision (dh <= 0) is discontinuous -> must match op-for-op.
#pragma clang fp contract(off)

static constexpr int Bc    = 512;
static constexpr int NPTSc = 2048;
static constexpr int Hc    = 256;
static constexpr int Wc    = 256;
static constexpr float DMAXF = 6.4f;
// Fixed staging window: 48 rows x 64 cols per plane. 6 planes * 3072 * 4B =
// 72 KiB LDS -> 2 blocks/CU (16 waves). 1024 points' bbox (sigma ~6 cells,
// range ~6.5 sigma ~ 41 cells) fits 46x62 budget with P(fallback) ~ 0.1%.
static constexpr int WROWS = 48;
static constexpr int WCOLS = 64;
static constexpr int CELLS = WROWS * WCOLS;   // 3072

__device__ __forceinline__ float bl(float g00, float g01, float g10, float g11,
                                    float wi, float wj) {
#pragma clang fp contract(off)
    // exact op ordering of the reference
    return g00 * (1.0f - wi) * (1.0f - wj)
         + g01 * (1.0f - wi) * wj
         + g10 * wi * (1.0f - wj)
         + g11 * wi * wj;
}

__global__ __launch_bounds__(512, 4)
void phys_points(const float* __restrict__ x, const float* __restrict__ xd,
                 const float* __restrict__ R, const float* __restrict__ omega,
                 const float* __restrict__ rp,
                 const float* __restrict__ zg, const float* __restrict__ zgg,
                 const float* __restrict__ kg, const float* __restrict__ dg,
                 const float* __restrict__ mug,
                 const int* __restrict__ dparts, const float* __restrict__ ctrl,
                 float* __restrict__ outFs, float* __restrict__ outFf,
                 float* __restrict__ partial)
{
#pragma clang fp contract(off)
    __shared__ float sg[6 * CELLS];
    __shared__ int sbox[4];          // min_i, max_i, min_j, max_j

    const int tid = threadIdx.x;
    const int b = blockIdx.x >> 1;               // 2 blocks per batch
    const int nb = ((blockIdx.x & 1) << 10) + tid;   // first point; second is +512

    // per-batch scalars (broadcast loads, L1-served)
    float xb0 = x[b * 3 + 0], xb1 = x[b * 3 + 1], xb2 = x[b * 3 + 2];
    float xd0 = xd[b * 3 + 0], xd1 = xd[b * 3 + 1], xd2 = xd[b * 3 + 2];
    float om0 = omega[b * 3 + 0], om1 = omega[b * 3 + 1], om2 = omega[b * 3 + 2];
    float R00 = R[b * 9 + 0], R01 = R[b * 9 + 1], R02 = R[b * 9 + 2];
    float R10 = R[b * 9 + 3], R11 = R[b * 9 + 4], R12 = R[b * 9 + 5];
    float R20 = R[b * 9 + 6], R21 = R[b * 9 + 7], R22 = R[b * 9 + 8];

    // thrust dir = normalize(R[:,0])  (batch-uniform, hoisted)
    float t0 = R00, t1 = R10, t2 = R20;
    float tn = sqrtf(t0 * t0 + t1 * t1 + t2 * t2);
    t0 /= tn; t1 /= tn; t2 /= tn;

    // ---- phase 1: load points, compute gather indices, block bbox ----
    float pa[2][3];
    int i0a[2], j0a[2];
    #pragma unroll
    for (int k = 0; k < 2; ++k) {
        const int n = nb + (k << 9);
        const int pbase = (b * NPTSc + n) * 3;
        pa[k][0] = rp[pbase + 0];
        pa[k][1] = rp[pbase + 1];
        pa[k][2] = rp[pbase + 2];
        float xp0 = (R00 * pa[k][0] + R01 * pa[k][1] + R02 * pa[k][2]) + xb0;
        float xp1 = (R10 * pa[k][0] + R11 * pa[k][1] + R12 * pa[k][2]) + xb1;
        float gi = (xp0 + DMAXF) / (2.0f * DMAXF) * 255.0f;
        gi = fminf(fmaxf(gi, 0.0f), 255.0f);
        float gj = (xp1 + DMAXF) / (2.0f * DMAXF) * 255.0f;
        gj = fminf(fmaxf(gj, 0.0f), 255.0f);
        int i0 = (int)floorf(gi); i0 = min(max(i0, 0), Hc - 2);
        int j0 = (int)floorf(gj); j0 = min(max(j0, 0), Wc - 2);
        i0a[k] = i0; j0a[k] = j0;
    }

    int mni = min(i0a[0], i0a[1]), mxi = max(i0a[0], i0a[1]);
    int mnj = min(j0a[0], j0a[1]), mxj = max(j0a[0], j0a[1]);
    #pragma unroll
    for (int off = 32; off > 0; off >>= 1) {
        mni = min(mni, __shfl_xor(mni, off, 64));
        mxi = max(mxi, __shfl_xor(mxi, off, 64));
        mnj = min(mnj, __shfl_xor(mnj, off, 64));
        mxj = max(mxj, __shfl_xor(mxj, off, 64));
    }
    if (tid == 0) { sbox[0] = 255; sbox[1] = 0; sbox[2] = 255; sbox[3] = 0; }
    __syncthreads();
    if ((tid & 63) == 0) {
        atomicMin(&sbox[0], mni); atomicMax(&sbox[1], mxi);
        atomicMin(&sbox[2], mnj); atomicMax(&sbox[3], mxj);
    }
    __syncthreads();
    const int bmin_i = sbox[0], bmin_j = sbox[2];
    const int ih = sbox[1] - bmin_i + 2;     // rows incl. the +1 corner row
    const int jw = sbox[3] - bmin_j + 2;     // cols incl. the +1 corner col
    const bool use_lds = (ih <= WROWS) && (jw <= WCOLS);   // block-uniform

    const int gb  = b * (Hc * Wc);
    const int gb2 = b * (2 * Hc * Wc);
    const float* planes[6] = { zg + gb, kg + gb, dg + gb, mug + gb,
                               zgg + gb2, zgg + gb2 + Hc * Wc };

    // ---- phase 2: coalesced fixed-geometry staging of the 6 planes ----
    if (use_lds) {
        const int c  = tid & 63;          // one wave = one full 64-col row
        const int r0 = tid >> 6;          // 0..7
        const int gcol = bmin_j + c;
        const bool cok = (gcol < Wc);
        #pragma unroll
        for (int p = 0; p < 6; ++p) {
            const float* src = planes[p] + bmin_j;
            float* dst = sg + p * CELLS + c;
            #pragma unroll
            for (int pass = 0; pass < WROWS / 8; ++pass) {
                const int r = r0 + pass * 8;
                const int grow = bmin_i + r;
                if (cok && grow < Hc)
                    dst[r * WCOLS] = src[grow * Wc + c];
            }
        }
        __syncthreads();
    }

    // ---- phase 3: per-point physics (2 points per thread) ----
    float vsum[9];
    #pragma unroll
    for (int k = 0; k < 9; ++k) vsum[k] = 0.0f;

    #pragma unroll
    for (int k = 0; k < 2; ++k) {
        const int n = nb + (k << 9);
        const int pbase = (b * NPTSc + n) * 3;
        const float p0 = pa[k][0], p1 = pa[k][1], p2 = pa[k][2];

        const int part = dparts[n];
        const float cpart = ctrl[b * 4 + part];

        // x_points = R @ p + x  (left-to-right sum, then add x)
        float xp0 = (R00 * p0 + R01 * p1 + R02 * p2) + xb0;
        float xp1 = (R10 * p0 + R11 * p1 + R12 * p2) + xb1;
        float xp2 = (R20 * p0 + R21 * p1 + R22 * p2) + xb2;

        // r = x_points - x  (reference recomputes incl. the +x/-x round-trip)
        float rx = xp0 - xb0, ry = xp1 - xb1, rz = xp2 - xb2;

        // bilinear weights (indices recomputed identically to phase 1)
        float gi = (xp0 + DMAXF) / (2.0f * DMAXF) * 255.0f;
        gi = fminf(fmaxf(gi, 0.0f), 255.0f);
        float gj = (xp1 + DMAXF) / (2.0f * DMAXF) * 255.0f;
        gj = fminf(fmaxf(gj, 0.0f), 255.0f);
        const int i0 = i0a[k], j0 = j0a[k];
        float wi = gi - (float)i0;
        float wj = gj - (float)j0;

        float cv[6][4];   // 4 corner values for each of the 6 planes
        if (use_lds) {
            const int la = (i0 - bmin_i) * WCOLS + (j0 - bmin_j);
            #pragma unroll
            for (int p = 0; p < 6; ++p) {
                const float* s = sg + p * CELLS + la;
                cv[p][0] = s[0];     cv[p][1] = s[1];          // ds_read2_b32
                cv[p][2] = s[WCOLS]; cv[p][3] = s[WCOLS + 1];  // ds_read2_b32
            }
        } else {
            // rare oversized-bbox fallback: exact global-gather path
            const int la = i0 * Wc + j0;
            #pragma unroll
            for (int p = 0; p < 6; ++p) {
                const float* s = planes[p] + la;
                cv[p][0] = s[0];  cv[p][1] = s[1];
                cv[p][2] = s[Wc]; cv[p][3] = s[Wc + 1];
            }
        }

        float zp  = bl(cv[0][0], cv[0][1], cv[0][2], cv[0][3], wi, wj);
        float kp  = bl(cv[1][0], cv[1][1], cv[1][2], cv[1][3], wi, wj);
        float dpv = bl(cv[2][0], cv[2][1], cv[2][2], cv[2][3], wi, wj);
        float mup = bl(cv[3][0], cv[3][1], cv[3][2], cv[3][3], wi, wj);
        float gx  = bl(cv[4][0], cv[4][1], cv[4][2], cv[4][3], wi, wj);
        float gy  = bl(cv[5][0], cv[5][1], cv[5][2], cv[5][3], wi, wj);

        float dh = xp2 - zp;
        bool on_grid = (xp0 >= -DMAXF) && (xp0 <= DMAXF) &&
                       (xp1 >= -DMAXF) && (xp1 <= DMAXF);
        float contact = ((dh <= 0.0f) && on_grid) ? 1.0f : 0.0f;

        // surface normal
        float nx = -gx, ny = -gy, nz = 1.0f;
        float nn = sqrtf(nx * nx + ny * ny + nz * nz);
        nx /= nn; ny /= nn; nz /= nn;

        // point velocity: xd + omega x r
        float vx = xd0 + (om1 * rz - om2 * ry);
        float vy = xd1 + (om2 * rx - om0 * rz);
        float vz = xd2 + (om0 * ry - om1 * rx);

        float xdn = vx * nx + vy * ny + vz * nz;
        float s = -(kp * dh + dpv * xdn);
        const float scale = contact * (1.0f / 2048.0f);  // contact in {0,1}
        float Fs0 = (s * nx) * scale;
        float Fs1 = (s * ny) * scale;
        float Fs2 = (s * nz) * scale;

        float Nmag = sqrtf(Fs0 * Fs0 + Fs1 * Fs1 + Fs2 * Fs2);

        float dv0 = cpart * t0 - vx;
        float dv1 = cpart * t1 - vy;
        float dv2 = cpart * t2 - vz;
        float dvn = dv0 * nx + dv1 * ny + dv2 * nz;
        float dt0 = dv0 - dvn * nx;
        float dt1 = dv1 - dvn * ny;
        float dt2 = dv2 - dvn * nz;
        float mN = mup * Nmag;
        float Ff0 = mN * tanhf(dt0);
        float Ff1 = mN * tanhf(dt1);
        float Ff2 = mN * tanhf(dt2);

        // write per-point outputs (f32)
        outFs[pbase + 0] = Fs0;
        outFs[pbase + 1] = Fs1;
        outFs[pbase + 2] = Fs2;
        outFf[pbase + 0] = Ff0;
        outFf[pbase + 1] = Ff1;
        outFf[pbase + 2] = Ff2;

        // torque = cross(r, Fs + Ff); accumulate across this thread's points
        float Ft0 = Fs0 + Ff0, Ft1 = Fs1 + Ff1, Ft2 = Fs2 + Ff2;
        vsum[0] += ry * Ft2 - rz * Ft1;
        vsum[1] += rz * Ft0 - rx * Ft2;
        vsum[2] += rx * Ft1 - ry * Ft0;
        vsum[3] += Fs0; vsum[4] += Fs1; vsum[5] += Fs2;
        vsum[6] += Ff0; vsum[7] += Ff1; vsum[8] += Ff2;
    }

    // wave-64 butterfly reduction, then wave-leader writes its partial slot
    // (no atomics, no workspace memset: every slot written every launch)
    #pragma unroll
    for (int kk = 0; kk < 9; ++kk) {
        float v = vsum[kk];
        #pragma unroll
        for (int off = 32; off > 0; off >>= 1)
            v += __shfl_xor(v, off, 64);
        vsum[kk] = v;
    }
    if ((tid & 63) == 0) {
        const int widx = ((blockIdx.x & 1) << 3) + (tid >> 6);   // 0..15/batch
        float* pb = partial + ((size_t)(b * 16 + widx)) * 9;
        #pragma unroll
        for (int kk = 0; kk < 9; ++kk) pb[kk] = vsum[kk];
    }
}

__global__ __launch_bounds__(64)
void phys_final(const float* __restrict__ xd, const float* __restrict__ Imat,
                const float* __restrict__ partial,
                float* __restrict__ out_xd, float* __restrict__ out_xdd,
                float* __restrict__ out_omd)
{
#pragma clang fp contract(off)
    const int b = blockIdx.x;
    const int lane = threadIdx.x;

    float v[9];
    if (lane < 16) {
        const float* pb = partial + ((size_t)(b * 16 + lane)) * 9;
        #pragma unroll
        for (int k = 0; k < 9; ++k) v[k] = pb[k];
    } else {
        #pragma unroll
        for (int k = 0; k < 9; ++k) v[k] = 0.0f;
    }
    #pragma unroll
    for (int k = 0; k < 9; ++k) {
        float t = v[k];
        #pragma unroll
        for (int off = 32; off > 0; off >>= 1)
            t += __shfl_xor(t, off, 64);
        v[k] = t;
    }

    if (lane == 0) {
        float tq0 = v[0], tq1 = v[1], tq2 = v[2];
        float sFs0 = v[3], sFs1 = v[4], sFs2 = v[5];
        float sFf0 = v[6], sFf1 = v[7], sFf2 = v[8];

        float a00 = Imat[b * 9 + 0], a01 = Imat[b * 9 + 1], a02 = Imat[b * 9 + 2];
        float a10 = Imat[b * 9 + 3], a11 = Imat[b * 9 + 4], a12 = Imat[b * 9 + 5];
        float a20 = Imat[b * 9 + 6], a21 = Imat[b * 9 + 7], a22 = Imat[b * 9 + 8];

        // adjugate / determinant inverse (I is well-conditioned: A A^T + 2I)
        float c00 = a11 * a22 - a12 * a21;
        float c01 = a02 * a21 - a01 * a22;
        float c02 = a01 * a12 - a02 * a11;
        float c10 = a12 * a20 - a10 * a22;
        float c11 = a00 * a22 - a02 * a20;
        float c12 = a02 * a10 - a00 * a12;
        float c20 = a10 * a21 - a11 * a20;
        float c21 = a01 * a20 - a00 * a21;
        float c22 = a00 * a11 - a01 * a10;
        float det = a00 * c00 + a01 * c10 + a02 * c20;
        float id = 1.0f / det;

        float od0 = (c00 * tq0 + c01 * tq1 + c02 * tq2) * id;
        float od1 = (c10 * tq0 + c11 * tq1 + c12 * tq2) * id;
        float od2 = (c20 * tq0 + c21 * tq1 + c22 * tq2) * id;

        // F_cog = (grav + sum Fs) + sum Ff ; xdd = F_cog / MASS
        float fc0 = (0.0f + sFs0) + sFf0;
        float fc1 = (0.0f + sFs1) + sFf1;
        float fc2 = (-40.0f * 9.8f + sFs2) + sFf2;
        float xdd0 = fc0 / 40.0f, xdd1 = fc1 / 40.0f, xdd2 = fc2 / 40.0f;

        out_xd[b * 3 + 0] = xd[b * 3 + 0];
        out_xd[b * 3 + 1] = xd[b * 3 + 1];
        out_xd[b * 3 + 2] = xd[b * 3 + 2];
        out_xdd[b * 3 + 0] = xdd0;
        out_xdd[b * 3 + 1] = xdd1;
        out_xdd[b * 3 + 2] = xdd2;
        out_omd[b * 3 + 0] = od0;
        out_omd[b * 3 + 1] = od1;
        out_omd[b * 3 + 2] = od2;
    }
}

extern "C" void kernel_launch(void* const* d_in, const int* in_sizes, int n_in,
                              void* d_out, int out_size, void* d_ws, size_t ws_size,
                              hipStream_t stream)
{
    const float* x    = (const float*)d_in[0];
    const float* xd   = (const float*)d_in[1];
    const float* R    = (const float*)d_in[2];
    const float* om   = (const float*)d_in[3];
    const float* Imat = (const float*)d_in[4];
    const float* rp   = (const float*)d_in[5];
    const float* zg   = (const float*)d_in[6];
    const float* zgg  = (const float*)d_in[7];
    const float* kg   = (const float*)d_in[8];
    const float* dg   = (const float*)d_in[9];
    const float* mug  = (const float*)d_in[10];
    const int* dparts = (const int*)d_in[11];
    const float* ctrl = (const float*)d_in[12];

    float* out = (float*)d_out;
    const int B3 = Bc * 3;
    float* out_xd  = out;
    float* out_xdd = out + B3;
    float* out_omd = out + 2 * B3;
    float* outFs   = out + 3 * B3;
    float* outFf   = out + 3 * B3 + (size_t)Bc * NPTSc * 3;

    // per-wave partials: Bc * 16 waves * 9 floats = 288 KiB of workspace.
    // Every slot is written unconditionally each launch -> no memset needed.
    float* partial = (float*)d_ws;

    phys_points<<<Bc * 2, 512, 0, stream>>>(
        x, xd, R, om, rp, zg, zgg, kg, dg, mug, dparts, ctrl, outFs, outFf, partial);
    phys_final<<<Bc, 64, 0, stream>>>(
        xd, Imat, partial, out_xd, out_xdd, out_omd);
}

// Round 3
// 557.673 us; speedup vs baseline: 1.2435x; 1.0519x over previous
//
#include <hip/hip_runtime.h>

// Contact-critical math (xp, grid indices/weights, zp bilerp, dh<=0) is kept
// op-for-op identical to the numpy f32 reference: no FMA contraction, IEEE
// divides, exact op order. Continuous-only math (normal dir, friction tanh,
// non-contact bilerps) uses fast native ops (rcp/rsq/exp2): <=~1e-6 abs error,
// 3 orders below the stable 2^-7 absmax.
#pragma clang fp contract(off)

static constexpr int Bc    = 512;
static constexpr int NPTSc = 2048;
static constexpr int Hc    = 256;
static constexpr int Wc    = 256;
static constexpr float DMAXF = 6.4f;
// Staging window: 52 rows (multiple of 4) x 64 cols. 6 planes * 3328 * 4B =
// 78 KiB LDS -> exactly 2 blocks/CU (160 KiB). 2048 points' i-range ~6.6
// sigma ~ 40 cells; 50-cell budget = 8.4 sigma -> fallback ~never.
static constexpr int WROWS = 52;
static constexpr int WCOLS = 64;
static constexpr int CELLS = WROWS * WCOLS;   // 3328
static constexpr int PPT   = 4;               // points per thread

__device__ __forceinline__ float ftanh(float v) {
    // tanh(v) = sign(v) * (1 - 2/(exp2(2*log2e*|v|)+1)); exp2/rcp are 1-ulp
    // native ops. |v| large -> e=inf -> r=1 (correct saturation).
    float e = __builtin_amdgcn_exp2f(fabsf(v) * 2.885390082f);
    float r = 1.0f - 2.0f * __builtin_amdgcn_rcpf(e + 1.0f);
    return copysignf(r, v);
}

__global__ __launch_bounds__(512, 4)
void phys_all(const float* __restrict__ x, const float* __restrict__ xd,
              const float* __restrict__ R, const float* __restrict__ omega,
              const float* __restrict__ Imat,
              const float* __restrict__ rp,
              const float* __restrict__ zg, const float* __restrict__ zgg,
              const float* __restrict__ kg, const float* __restrict__ dg,
              const float* __restrict__ mug,
              const int* __restrict__ dparts, const float* __restrict__ ctrl,
              float* __restrict__ outFs, float* __restrict__ outFf,
              float* __restrict__ out_xd, float* __restrict__ out_xdd,
              float* __restrict__ out_omd)
{
#pragma clang fp contract(off)
    __shared__ float sg[6 * CELLS];
    __shared__ int sbox[4];              // min_i, max_i, min_j, max_j
    __shared__ float red[8 * 9];         // per-wave partials

    const int tid = threadIdx.x;
    const int b = blockIdx.x;            // 1 block == 1 batch

    // per-batch scalars (uniform, L1/sL1-served)
    float xb0 = x[b * 3 + 0], xb1 = x[b * 3 + 1], xb2 = x[b * 3 + 2];
    float xd0 = xd[b * 3 + 0], xd1 = xd[b * 3 + 1], xd2 = xd[b * 3 + 2];
    float om0 = omega[b * 3 + 0], om1 = omega[b * 3 + 1], om2 = omega[b * 3 + 2];
    float R00 = R[b * 9 + 0], R01 = R[b * 9 + 1], R02 = R[b * 9 + 2];
    float R10 = R[b * 9 + 3], R11 = R[b * 9 + 4], R12 = R[b * 9 + 5];
    float R20 = R[b * 9 + 6], R21 = R[b * 9 + 7], R22 = R[b * 9 + 8];

    // thrust dir = normalize(R[:,0])  (batch-uniform; keep IEEE exact, cheap)
    float t0 = R00, t1 = R10, t2 = R20;
    float tn = sqrtf(t0 * t0 + t1 * t1 + t2 * t2);
    t0 /= tn; t1 /= tn; t2 /= tn;

    // ---- phase 1: points -> exact indices/weights; block bbox ----
    float xpA[PPT][3];
    float wiA[PPT], wjA[PPT], cpA[PPT];
    int pkA[PPT];                        // i0 | j0<<8 | on_grid<<16
    int mni = 255, mxi = 0, mnj = 255, mxj = 0;
    #pragma unroll
    for (int k = 0; k < PPT; ++k) {
        const int n = tid + (k << 9);
        const int pb3 = (b * NPTSc + n) * 3;
        float p0 = rp[pb3 + 0], p1 = rp[pb3 + 1], p2 = rp[pb3 + 2];
        cpA[k] = ctrl[b * 4 + dparts[n]];

        // x_points = R @ p + x  (exact op order)
        float xp0 = (R00 * p0 + R01 * p1 + R02 * p2) + xb0;
        float xp1 = (R10 * p0 + R11 * p1 + R12 * p2) + xb1;
        float xp2 = (R20 * p0 + R21 * p1 + R22 * p2) + xb2;
        xpA[k][0] = xp0; xpA[k][1] = xp1; xpA[k][2] = xp2;

        // exact IEEE divides: these feed indices/weights -> contact
        float gi = (xp0 + DMAXF) / (2.0f * DMAXF) * 255.0f;
        gi = fminf(fmaxf(gi, 0.0f), 255.0f);
        float gj = (xp1 + DMAXF) / (2.0f * DMAXF) * 255.0f;
        gj = fminf(fmaxf(gj, 0.0f), 255.0f);
        int i0 = (int)floorf(gi); i0 = min(max(i0, 0), Hc - 2);
        int j0 = (int)floorf(gj); j0 = min(max(j0, 0), Wc - 2);
        wiA[k] = gi - (float)i0;
        wjA[k] = gj - (float)j0;
        bool og = (xp0 >= -DMAXF) && (xp0 <= DMAXF) &&
                  (xp1 >= -DMAXF) && (xp1 <= DMAXF);
        pkA[k] = i0 | (j0 << 8) | (og ? (1 << 16) : 0);
        mni = min(mni, i0); mxi = max(mxi, i0);
        mnj = min(mnj, j0); mxj = max(mxj, j0);
    }

    #pragma unroll
    for (int off = 32; off > 0; off >>= 1) {
        mni = min(mni, __shfl_xor(mni, off, 64));
        mxi = max(mxi, __shfl_xor(mxi, off, 64));
        mnj = min(mnj, __shfl_xor(mnj, off, 64));
        mxj = max(mxj, __shfl_xor(mxj, off, 64));
    }
    if (tid == 0) { sbox[0] = 255; sbox[1] = 0; sbox[2] = 255; sbox[3] = 0; }
    __syncthreads();
    if ((tid & 63) == 0) {
        atomicMin(&sbox[0], mni); atomicMax(&sbox[1], mxi);
        atomicMin(&sbox[2], mnj); atomicMax(&sbox[3], mxj);
    }
    __syncthreads();
    const int bi = sbox[0];
    const int bj = sbox[2] & ~3;                 // 16B-align window cols
    const int ih = sbox[1] - bi + 2;
    const int jw = sbox[3] - bj + 2;
    const bool use_lds = (ih <= WROWS) && (jw <= WCOLS);  // block-uniform

    const int gb  = b * (Hc * Wc);
    const int gb2 = b * (2 * Hc * Wc);
    const float* planes[6] = { zg + gb, kg + gb, dg + gb, mug + gb,
                               zgg + gb2, zgg + gb2 + Hc * Wc };

    // ---- phase 2: float4 staging, 4 rows per wave-instr, lane-linear LDS ----
    if (use_lds) {
        const int w = tid >> 6, l = tid & 63;
        const int rsub = l >> 4;                 // row within 4-row group
        const int csub = (l & 15) << 2;          // col 0,4,...,60
        const int jcol = min(bj + csub, Wc - 4); // clamp: clamped cells never read
        const int ngrp = (ih + 3) >> 2;
        for (int g = w; g < ngrp; g += 8) {
            const int r = (g << 2) + rsub;       // r <= 51 < WROWS
            const int grow = min(bi + r, Hc - 1);
            #pragma unroll
            for (int p = 0; p < 6; ++p) {
                const float4 v = *reinterpret_cast<const float4*>(
                    planes[p] + grow * Wc + jcol);
                *reinterpret_cast<float4*>(&sg[p * CELLS + r * WCOLS + csub]) = v;
            }
        }
        __syncthreads();
    }

    // ---- phase 3: per-point physics ----
    float vsum[9];
    #pragma unroll
    for (int c = 0; c < 9; ++c) vsum[c] = 0.0f;

    #pragma unroll
    for (int k = 0; k < PPT; ++k) {
        const int n = tid + (k << 9);
        const int pb3 = (b * NPTSc + n) * 3;
        const int i0 = pkA[k] & 255;
        const int j0 = (pkA[k] >> 8) & 255;
        const bool og = (pkA[k] >> 16) & 1;
        const float wi = wiA[k], wj = wjA[k];

        float cv[6][4];
        if (use_lds) {
            const int la = (i0 - bi) * WCOLS + (j0 - bj);
            #pragma unroll
            for (int p = 0; p < 6; ++p) {
                const float* s = sg + p * CELLS + la;
                cv[p][0] = s[0];     cv[p][1] = s[1];          // ds_read2_b32
                cv[p][2] = s[WCOLS]; cv[p][3] = s[WCOLS + 1];  // ds_read2_b32
            }
        } else {
            const int la = i0 * Wc + j0;
            #pragma unroll
            for (int p = 0; p < 6; ++p) {
                const float* s = planes[p] + la;
                cv[p][0] = s[0];  cv[p][1] = s[1];
                cv[p][2] = s[Wc]; cv[p][3] = s[Wc + 1];
            }
        }

        const float omwi = 1.0f - wi, omwj = 1.0f - wj;
        // zp: exact reference op order (feeds the contact decision)
        float zp = cv[0][0] * omwi * omwj + cv[0][1] * omwi * wj
                 + cv[0][2] * wi * omwj   + cv[0][3] * wi * wj;
        // continuous planes: hoisted weights (~1 ulp difference, safe)
        const float w00 = omwi * omwj, w01 = omwi * wj;
        const float w10 = wi * omwj,   w11 = wi * wj;
        float kp  = cv[1][0]*w00 + cv[1][1]*w01 + cv[1][2]*w10 + cv[1][3]*w11;
        float dpv = cv[2][0]*w00 + cv[2][1]*w01 + cv[2][2]*w10 + cv[2][3]*w11;
        float mup = cv[3][0]*w00 + cv[3][1]*w01 + cv[3][2]*w10 + cv[3][3]*w11;
        float gx  = cv[4][0]*w00 + cv[4][1]*w01 + cv[4][2]*w10 + cv[4][3]*w11;
        float gy  = cv[5][0]*w00 + cv[5][1]*w01 + cv[5][2]*w10 + cv[5][3]*w11;

        const float xp0 = xpA[k][0], xp1 = xpA[k][1], xp2 = xpA[k][2];
        const float rx = xp0 - xb0, ry = xp1 - xb1, rz = xp2 - xb2;

        float dh = xp2 - zp;                               // exact
        float contact = ((dh <= 0.0f) && og) ? 1.0f : 0.0f;

        // normal via rsq (continuous-only downstream)
        float nx = -gx, ny = -gy;
        float invn = __builtin_amdgcn_rsqf(nx * nx + ny * ny + 1.0f);
        nx *= invn; ny *= invn;
        const float nz = invn;

        // point velocity: xd + omega x r
        float vx = xd0 + (om1 * rz - om2 * ry);
        float vy = xd1 + (om2 * rx - om0 * rz);
        float vz = xd2 + (om0 * ry - om1 * rx);

        float xdn = vx * nx + vy * ny + vz * nz;
        float s = -(kp * dh + dpv * xdn);
        const float scale = contact * (1.0f / 2048.0f);    // exact pow2
        float Fs0 = (s * nx) * scale;
        float Fs1 = (s * ny) * scale;
        float Fs2 = (s * nz) * scale;

        float Nmag = sqrtf(Fs0 * Fs0 + Fs1 * Fs1 + Fs2 * Fs2);

        const float cp = cpA[k];
        float dv0 = cp * t0 - vx;
        float dv1 = cp * t1 - vy;
        float dv2 = cp * t2 - vz;
        float dvn = dv0 * nx + dv1 * ny + dv2 * nz;
        float dt0 = dv0 - dvn * nx;
        float dt1 = dv1 - dvn * ny;
        float dt2 = dv2 - dvn * nz;
        float mN = mup * Nmag;
        float Ff0 = mN * ftanh(dt0);
        float Ff1 = mN * ftanh(dt1);
        float Ff2 = mN * ftanh(dt2);

        outFs[pb3 + 0] = Fs0;
        outFs[pb3 + 1] = Fs1;
        outFs[pb3 + 2] = Fs2;
        outFf[pb3 + 0] = Ff0;
        outFf[pb3 + 1] = Ff1;
        outFf[pb3 + 2] = Ff2;

        float Ft0 = Fs0 + Ff0, Ft1 = Fs1 + Ff1, Ft2 = Fs2 + Ff2;
        vsum[0] += ry * Ft2 - rz * Ft1;
        vsum[1] += rz * Ft0 - rx * Ft2;
        vsum[2] += rx * Ft1 - ry * Ft0;
        vsum[3] += Fs0; vsum[4] += Fs1; vsum[5] += Fs2;
        vsum[6] += Ff0; vsum[7] += Ff1; vsum[8] += Ff2;
    }

    // ---- block epilogue: reduce 8 waves, finalize batch in-place ----
    #pragma unroll
    for (int c = 0; c < 9; ++c) {
        float v = vsum[c];
        #pragma unroll
        for (int off = 32; off > 0; off >>= 1)
            v += __shfl_xor(v, off, 64);
        vsum[c] = v;
    }
    if ((tid & 63) == 0) {
        const int w = tid >> 6;
        #pragma unroll
        for (int c = 0; c < 9; ++c) red[w * 9 + c] = vsum[c];
    }
    __syncthreads();

    if (tid == 0) {
        float sum[9];
        #pragma unroll
        for (int c = 0; c < 9; ++c) {
            float s = red[c];
            #pragma unroll
            for (int w = 1; w < 8; ++w) s += red[w * 9 + c];
            sum[c] = s;
        }
        float tq0 = sum[0], tq1 = sum[1], tq2 = sum[2];
        float sFs0 = sum[3], sFs1 = sum[4], sFs2 = sum[5];
        float sFf0 = sum[6], sFf1 = sum[7], sFf2 = sum[8];

        float a00 = Imat[b * 9 + 0], a01 = Imat[b * 9 + 1], a02 = Imat[b * 9 + 2];
        float a10 = Imat[b * 9 + 3], a11 = Imat[b * 9 + 4], a12 = Imat[b * 9 + 5];
        float a20 = Imat[b * 9 + 6], a21 = Imat[b * 9 + 7], a22 = Imat[b * 9 + 8];

        // adjugate / determinant inverse (I is well-conditioned: A A^T + 2I)
        float c00 = a11 * a22 - a12 * a21;
        float c01 = a02 * a21 - a01 * a22;
        float c02 = a01 * a12 - a02 * a11;
        float c10 = a12 * a20 - a10 * a22;
        float c11 = a00 * a22 - a02 * a20;
        float c12 = a02 * a10 - a00 * a12;
        float c20 = a10 * a21 - a11 * a20;
        float c21 = a01 * a20 - a00 * a21;
        float c22 = a00 * a11 - a01 * a10;
        float det = a00 * c00 + a01 * c10 + a02 * c20;
        float id = 1.0f / det;

        float od0 = (c00 * tq0 + c01 * tq1 + c02 * tq2) * id;
        float od1 = (c10 * tq0 + c11 * tq1 + c12 * tq2) * id;
        float od2 = (c20 * tq0 + c21 * tq1 + c22 * tq2) * id;

        float fc0 = (0.0f + sFs0) + sFf0;
        float fc1 = (0.0f + sFs1) + sFf1;
        float fc2 = (-40.0f * 9.8f + sFs2) + sFf2;

        out_xd[b * 3 + 0] = xd0;
        out_xd[b * 3 + 1] = xd1;
        out_xd[b * 3 + 2] = xd2;
        out_xdd[b * 3 + 0] = fc0 / 40.0f;
        out_xdd[b * 3 + 1] = fc1 / 40.0f;
        out_xdd[b * 3 + 2] = fc2 / 40.0f;
        out_omd[b * 3 + 0] = od0;
        out_omd[b * 3 + 1] = od1;
        out_omd[b * 3 + 2] = od2;
    }
}

extern "C" void kernel_launch(void* const* d_in, const int* in_sizes, int n_in,
                              void* d_out, int out_size, void* d_ws, size_t ws_size,
                              hipStream_t stream)
{
    const float* x    = (const float*)d_in[0];
    const float* xd   = (const float*)d_in[1];
    const float* R    = (const float*)d_in[2];
    const float* om   = (const float*)d_in[3];
    const float* Imat = (const float*)d_in[4];
    const float* rp   = (const float*)d_in[5];
    const float* zg   = (const float*)d_in[6];
    const float* zgg  = (const float*)d_in[7];
    const float* kg   = (const float*)d_in[8];
    const float* dg   = (const float*)d_in[9];
    const float* mug  = (const float*)d_in[10];
    const int* dparts = (const int*)d_in[11];
    const float* ctrl = (const float*)d_in[12];

    float* out = (float*)d_out;
    const int B3 = Bc * 3;
    float* out_xd  = out;
    float* out_xdd = out + B3;
    float* out_omd = out + 2 * B3;
    float* outFs   = out + 3 * B3;
    float* outFf   = out + 3 * B3 + (size_t)Bc * NPTSc * 3;

    // single kernel: 1 block per batch; no workspace, no memset, one launch
    phys_all<<<Bc, 512, 0, stream>>>(
        x, xd, R, om, Imat, rp, zg, zgg, kg, dg, mug, dparts, ctrl,
        outFs, outFf, out_xd, out_xdd, out_omd);
}